// Round 2
// baseline (194.523 us; speedup 1.0000x reference)
//
#include <hip/hip_runtime.h>
#include <hip/hip_bf16.h>

// Problem: B=32, S=2048, D=512, FULL=60000.
// vals[b,s] = dot(h[b,s,:], w) + bias;  out[b, gene_pos[b,s]] = vals  (pos<FULL)
// Memory-bound: 134 MB mandatory h read (~22 us at 6.3 TB/s). dur_us is
// dominated by harness reset fills (~77 us x2 for 536 MB d_ws poison, seen in
// rocprof R1); our controllable slice is memset (1.3 us) + kernel (~25 us).
// R2: nontemporal h loads (stream-once, keep L2 for out RMW sectors + w),
// 2 tokens per wave for deeper MLP and half the wave/scatter overhead.

#define B_DIM 32
#define S_DIM 2048
#define D_DIM 512
#define FULL_LEN 60000

typedef __attribute__((ext_vector_type(4))) float vfloat4;

__global__ __launch_bounds__(256) void conv_scatter_kernel(
        const float* __restrict__ h,
        const int* __restrict__ gene_pos,
        const float* __restrict__ w,
        const float* __restrict__ bias,
        float* __restrict__ out) {
    const int wave = threadIdx.x >> 6;               // 0..3
    const int lane = threadIdx.x & 63;
    // 2 tokens per wave, 8 per block
    const int t0 = (blockIdx.x << 3) + (wave << 1);  // first token of this wave

    const vfloat4* hp0 = (const vfloat4*)(h + (size_t)t0 * D_DIM);
    const vfloat4* hp1 = hp0 + (D_DIM / 4);          // token t0+1
    const vfloat4* wp  = (const vfloat4*)w;

    // lane i covers elements [8i, 8i+8): two float4 per token
    const int v = lane << 1;

    // issue all 4 h loads (nontemporal: h is streamed exactly once)
    vfloat4 a0 = __builtin_nontemporal_load(hp0 + v);
    vfloat4 a1 = __builtin_nontemporal_load(hp0 + v + 1);
    vfloat4 b0 = __builtin_nontemporal_load(hp1 + v);
    vfloat4 b1 = __builtin_nontemporal_load(hp1 + v + 1);
    // w stays cached (L1-resident, 2 KB)
    vfloat4 w0 = wp[v];
    vfloat4 w1 = wp[v + 1];

    float s0 = a0.x * w0.x + a0.y * w0.y + a0.z * w0.z + a0.w * w0.w
             + a1.x * w1.x + a1.y * w1.y + a1.z * w1.z + a1.w * w1.w;
    float s1 = b0.x * w0.x + b0.y * w0.y + b0.z * w0.z + b0.w * w0.w
             + b1.x * w1.x + b1.y * w1.y + b1.z * w1.z + b1.w * w1.w;

    // wave64 butterfly reductions
    #pragma unroll
    for (int off = 32; off > 0; off >>= 1) {
        s0 += __shfl_xor(s0, off, 64);
        s1 += __shfl_xor(s1, off, 64);
    }

    if (lane == 0) {
        const float bb = bias[0];
        const int brow = t0 >> 11;                   // both tokens same row:
        // t0 is even and S=2048 is even, so t0 and t0+1 share brow only if
        // t0 % 2048 != 2047; t0 even => t0+1 <= row boundary only crossed at
        // odd->even transitions; since 2048 is even and t0 even, t0 and t0+1
        // are always in the same row.
        const int p0 = gene_pos[t0];
        const int p1 = gene_pos[t0 + 1];
        if (p0 < FULL_LEN) out[(size_t)brow * FULL_LEN + p0] = s0 + bb;
        if (p1 < FULL_LEN) out[(size_t)brow * FULL_LEN + p1] = s1 + bb;
    }
}

extern "C" void kernel_launch(void* const* d_in, const int* in_sizes, int n_in,
                              void* d_out, int out_size, void* d_ws, size_t ws_size,
                              hipStream_t stream) {
    const float* h        = (const float*)d_in[0];
    const int*   gene_pos = (const int*)d_in[1];
    const float* w        = (const float*)d_in[2];
    const float* bias     = (const float*)d_in[3];
    float* out = (float*)d_out;

    // d_out is re-poisoned to 0xAA before every timed launch: zero it.
    hipMemsetAsync(out, 0, (size_t)out_size * sizeof(float), stream);

    const int tokens = B_DIM * S_DIM;                // 65536
    const int blocks = tokens / 8;                   // 8 tokens per block
    conv_scatter_kernel<<<blocks, 256, 0, stream>>>(h, gene_pos, w, bias, out);
}